// Round 22
// baseline (67.344 us; speedup 1.0000x reference)
//
#include <hip/hip_runtime.h>
#include <hip/hip_bf16.h>

// ---------------------------------------------------------------------------
// DSTDGC R22.
// k0_proj / k2_out: unchanged from R21 (62.6 us best).
// k1_adj: output STAGED IN LDS -> full-line coalesced adjm writes (R11/R12
//   counters showed 57-64MB written for a 33.5MB output = partial-sector
//   amplification from 8B scattered stores).  m2s unioned with adjL (m2s
//   dead after upfront tanh); two t-halves; t-stride 1092 shorts (bank-
//   spread).  LDS 84.8KB, 1024 thr, grid 256 (geometry as R21).
// ---------------------------------------------------------------------------

typedef float  f32x4  __attribute__((ext_vector_type(4)));
typedef short  bf16x8 __attribute__((ext_vector_type(8)));
typedef short  bf16x4 __attribute__((ext_vector_type(4)));

static __device__ __forceinline__ short f2bf(float f) {
    __hip_bfloat16 h = __float2bfloat16(f);     // RNE; compiler packs pairs
    return *reinterpret_cast<short*>(&h);
}

static __device__ __forceinline__ float bf2f(short s) {
    return __uint_as_float(((unsigned)(unsigned short)s) << 16);
}

static __device__ __forceinline__ bf16x8 cvt8f(const float4 a, const float4 b) {
    bf16x8 r;
    r[0] = f2bf(a.x); r[1] = f2bf(a.y); r[2] = f2bf(a.z); r[3] = f2bf(a.w);
    r[4] = f2bf(b.x); r[5] = f2bf(b.y); r[6] = f2bf(b.z); r[7] = f2bf(b.w);
    return r;
}

static __device__ __forceinline__ bf16x8 cvt8(const float* p) {
    return cvt8f(*(const float4*)p, *(const float4*)(p + 4));
}

// tanh(x) = 1 - 2/(exp(2x)+1)
static __device__ __forceinline__ float tanh_fast(float x) {
    float e = __expf(2.0f * x);
    return 1.0f - 2.0f * __builtin_amdgcn_rcpf(e + 1.0f);
}

static __device__ __forceinline__ float dot4(float4 a, float4 b) {
    return a.x * b.x + a.y * b.y + a.z * b.z + a.w * b.w;
}

static __device__ __forceinline__ float alpha_decode(const int* p) {
    int raw = p[0];
    unsigned ur = (unsigned)(raw < 0 ? -raw : raw);
    return (ur < (1u << 23)) ? (float)raw : __int_as_float(raw);
}

static __device__ __forceinline__ bf16x8 fuse8(bf16x8 s, float4 a0, float4 a1,
                                               float ab) {
    bf16x8 r;
    r[0] = f2bf(bf2f(s[0]) + a0.x + ab);
    r[1] = f2bf(bf2f(s[1]) + a0.y + ab);
    r[2] = f2bf(bf2f(s[2]) + a0.z + ab);
    r[3] = f2bf(bf2f(s[3]) + a0.w + ab);
    r[4] = f2bf(bf2f(s[4]) + a1.x + ab);
    r[5] = f2bf(bf2f(s[5]) + a1.y + ab);
    r[6] = f2bf(bf2f(s[6]) + a1.z + ab);
    r[7] = f2bf(bf2f(s[7]) + a1.w + ab);
    return r;
}

#define MFMA16(a, b, c) __builtin_amdgcn_mfma_f32_16x16x32_bf16((a), (b), (c), 0, 0, 0)

// ---------------------------------------------------------------------------
// K0_proj: m-projections only.  Block b = n*8 + vc (v0 = vc*8), 512 thr.
// ---------------------------------------------------------------------------
__global__ __launch_bounds__(512) void k0_proj(
    const float* __restrict__ x,
    const float* __restrict__ w_m1, const float* __restrict__ b_m1,
    const float* __restrict__ w_m2, const float* __restrict__ b_m2,
    float* __restrict__ m1T, float* __restrict__ m2T)
{
    __shared__ float msT[4][8][68];     // [sel][vv][t], stride 68 (f4-aligned)

    const int b   = blockIdx.x;         // n*8 + vc
    const int n   = b >> 3;
    const int v0  = (b & 7) * 8;
    const int tid = threadIdx.x;
    const int tl  = tid >> 6;           // 0..7
    const int vv  = (tid >> 3) & 7;     // 0..7
    const int cg  = tid & 7;            // 0..7
    const int c0  = cg * 8;

    const float4 w10 = *(const float4*)(w_m1 + c0);
    const float4 w11 = *(const float4*)(w_m1 + c0 + 4);
    const float4 w20 = *(const float4*)(w_m1 + 64 + c0);
    const float4 w21 = *(const float4*)(w_m1 + 64 + c0 + 4);
    const float4 w30 = *(const float4*)(w_m2 + c0);
    const float4 w31 = *(const float4*)(w_m2 + c0 + 4);
    const float4 w40 = *(const float4*)(w_m2 + 64 + c0);
    const float4 w41 = *(const float4*)(w_m2 + 64 + c0 + 4);

#pragma unroll 2
    for (int it = 0; it < 8; ++it) {
        const int t = it * 8 + tl;
        const size_t R = ((size_t)(n * 64 + t)) * 64 + (v0 + vv);
        const float* xp = x + (R << 6) + c0;
        const float4 a0 = *(const float4*)xp;
        const float4 a1 = *(const float4*)(xp + 4);

        float s0 = dot4(a0, w10) + dot4(a1, w11);
        float s1 = dot4(a0, w20) + dot4(a1, w21);
        float s2 = dot4(a0, w30) + dot4(a1, w31);
        float s3 = dot4(a0, w40) + dot4(a1, w41);

#pragma unroll
        for (int m = 1; m < 8; m <<= 1) {
            s0 += __shfl_xor(s0, m);
            s1 += __shfl_xor(s1, m);
            s2 += __shfl_xor(s2, m);
            s3 += __shfl_xor(s3, m);
        }
        if (cg < 4) {                   // per-t regions disjoint -> no barrier
            float s = (cg == 0) ? s0 : (cg == 1) ? s1 : (cg == 2) ? s2 : s3;
            msT[cg][vv][t] = s;
        }
    }
    __syncthreads();

    {
        const int m   = tid >> 8;        // 0: m1, 1: m2
        const int rem = tid & 255;
        const int vv2 = rem >> 5;        // 0..7
        const int k0  = (rem & 31) * 4;  // 0..124
        const int r   = k0 >> 6;
        const int sel = m * 2 + r;
        const int t0  = k0 & 63;
        float4 val = *(const float4*)&msT[sel][vv2][t0];
        const float bias = (m == 0) ? b_m1[r] : b_m2[r];
        val.x += bias; val.y += bias; val.z += bias; val.w += bias;
        float* dst = ((m == 0) ? m1T : m2T) + n * 8192 + (v0 + vv2) * 128 + k0;
        *(float4*)dst = val;
    }
}

// ---------------------------------------------------------------------------
// K1: block (n, i-chunk of 16), 1024 thr, grid 256.
//   Upfront tanh -> bfr[4][4]; m2s dead -> adjL union; two t-halves with
//   LDS-staged output -> fully coalesced 2KB/t adjm writes.
// ---------------------------------------------------------------------------
__global__ __launch_bounds__(1024) void k1_adj(
    const float* __restrict__ w_rm,
    const float* __restrict__ m1T,  const float* __restrict__ m2T,
    const int* __restrict__ alpha_p,
    short* __restrict__ adjm)
{
    __shared__ short wrs[64 * 132];     // [t][k] bf16*alpha      (16.9 KB)
    __shared__ union {
        float m2s[64 * 132];            // [j][k] f32             (33.8 KB)
        short adjL[32 * 1092];          // [tloc][il(68 ea)]      (68.3 KB)
    } u;

    const int b   = blockIdx.x;         // n*4 + ic
    const int n   = b >> 2;
    const int i0  = (b & 3) * 16;
    const int tid = threadIdx.x;
    const int l = tid & 63, w = tid >> 6;       // w = 0..15
    const int lr = l & 15, lg = l >> 4;
    const int ig = i0 + w;

    const float alpha = alpha_decode(alpha_p);

    // ---- issue m1 row loads FIRST (latency hides under staging)
    float4 m1r[8];
#pragma unroll
    for (int kt = 0; kt < 4; ++kt) {
        const float* p = m1T + n * 8192 + ig * 128 + kt * 32 + lg * 8;
        m1r[kt * 2 + 0] = *(const float4*)p;
        m1r[kt * 2 + 1] = *(const float4*)(p + 4);
    }

    {
        const float4* src = (const float4*)(m2T + n * 8192);
        for (int it = tid; it < 2048; it += 1024) {
            int j = it >> 5, q = it & 31;
            *(float4*)(u.m2s + j * 132 + q * 4) = src[it];
        }
    }
    {
        const float4* src = (const float4*)w_rm;
        for (int it = tid; it < 2048; it += 1024) {
            int t = it >> 5, q = it & 31;
            float4 v = src[it];
            bf16x4 pv;
            pv[0] = f2bf(alpha * v.x);
            pv[1] = f2bf(alpha * v.y);
            pv[2] = f2bf(alpha * v.z);
            pv[3] = f2bf(alpha * v.w);
            *(bf16x4*)(wrs + t * 132 + q * 4) = pv;
        }
    }
    __syncthreads();

    // ---- ALL tanh fragments upfront (m1r dies here)
    bf16x8 bfr[4][4];                   // [jt][kt]
#pragma unroll
    for (int jt = 0; jt < 4; ++jt) {
        const float* m2row = u.m2s + (jt * 16 + lr) * 132;
#pragma unroll
        for (int kt = 0; kt < 4; ++kt) {
            const int k0 = kt * 32 + lg * 8;
            float4 b0 = *(const float4*)(m2row + k0);
            float4 b1 = *(const float4*)(m2row + k0 + 4);
            float4 a0 = m1r[kt * 2], a1 = m1r[kt * 2 + 1];
            bfr[jt][kt][0] = f2bf(tanh_fast(a0.x - b0.x));
            bfr[jt][kt][1] = f2bf(tanh_fast(a0.y - b0.y));
            bfr[jt][kt][2] = f2bf(tanh_fast(a0.z - b0.z));
            bfr[jt][kt][3] = f2bf(tanh_fast(a0.w - b0.w));
            bfr[jt][kt][4] = f2bf(tanh_fast(a1.x - b1.x));
            bfr[jt][kt][5] = f2bf(tanh_fast(a1.y - b1.y));
            bfr[jt][kt][6] = f2bf(tanh_fast(a1.z - b1.z));
            bfr[jt][kt][7] = f2bf(tanh_fast(a1.w - b1.w));
        }
    }
    __syncthreads();                    // m2s dead; adjL may now be written

#pragma unroll 1
    for (int qh = 0; qh < 2; ++qh) {
        // ---- MFMA for t-half, results -> adjL (conflict-light ds_write_b64)
#pragma unroll
        for (int qi = 0; qi < 2; ++qi) {
            const int q    = 2 * qh + qi;
            const int tq   = q * 16 + lr;
            const int tloc = tq - 32 * qh;      // 0..31
            bf16x8 af[4];
#pragma unroll
            for (int kt = 0; kt < 4; ++kt)
                af[kt] = *(const bf16x8*)(wrs + tq * 132 + kt * 32 + lg * 8);
            short* lbase = u.adjL + tloc * 1092 + w * 68 + lg * 4;
#pragma unroll
            for (int jt = 0; jt < 4; ++jt) {
                f32x4 acc = (f32x4){0.f, 0.f, 0.f, 0.f};
#pragma unroll
                for (int kt = 0; kt < 4; ++kt)
                    acc = MFMA16(bfr[jt][kt], af[kt], acc);     // D[j][t]
                bf16x4 pv;
                pv[0] = f2bf(acc[0]);
                pv[1] = f2bf(acc[1]);
                pv[2] = f2bf(acc[2]);
                pv[3] = f2bf(acc[3]);
                *(bf16x4*)(lbase + jt * 16) = pv;               // 8B ds_write
            }
        }
        __syncthreads();

        // ---- coalesced write-out of this t-half (full 2KB per t-page)
        {
            short* gbase = adjm + ((size_t)n << 18)
                         + ((size_t)(32 * qh) << 12) + (i0 << 6);
#pragma unroll
            for (int it = 0; it < 4; ++it) {
                const int c   = it * 1024 + tid;    // 0..4095
                const int tl2 = c >> 7;             // 0..31
                const int il  = (c >> 3) & 15;      // 0..15
                const int jc  = (c & 7) * 8;        // 0..56
                bf16x8 v = *(const bf16x8*)(u.adjL + tl2 * 1092 + il * 68 + jc);
                *(bf16x8*)(gbase + ((size_t)tl2 << 12) + il * 64 + jc) = v;
            }
        }
        __syncthreads();                // before next half overwrites adjL
    }
}

// ---------------------------------------------------------------------------
// K2: block = FOUR consecutive (n,t) pairs, 256 thr, grid 1024.  T14 depth-4.
//   x read DIRECTLY as f32 (L3-resident); cvt fused into staging.  (R19)
// ---------------------------------------------------------------------------
__global__ __launch_bounds__(256) void k2_out(
    const short* __restrict__ adjm, const float* __restrict__ x,
    const float* __restrict__ Ast,  const float* __restrict__ b_rm,
    const int* __restrict__ alpha_p,
    const float* __restrict__ w_f,  const float* __restrict__ b_f,
    float* __restrict__ out)
{
    __shared__ short adjs[64 * 72];     // [i][j] ready-adj bf16      (9.2 KB)
    __shared__ short xT[64 * 72 + 32];  // [c][j], off c*72+(c>>4)*8  (9.3 KB)
    __shared__ short P[64 * 104];       // [i][c]                    (13.3 KB)

    const int b   = blockIdx.x;         // pairs 4b .. 4b+3
    const int tid = threadIdx.x;
    const int l = tid & 63, w = tid >> 6;
    const int lr = l & 15, lg = l >> 4;

    const float alpha = alpha_decode(alpha_p);

    const int row0 = tid >> 3;          // 0..31
    const int row1 = row0 + 32;         // 32..63
    const int c8   = (tid & 7) * 8;
    const int jx   = tid >> 2;
    const int cx0  = (tid & 3) * 16;
    const int gx0  = (cx0 >> 4) * 8;

    // ---- w_f / b_f / ones fragments: shared across all 4 pairs
    const int o = w * 16 + lr;
    bf16x8 afw[3];
#pragma unroll
    for (int ks = 0; ks < 2; ++ks)
        afw[ks] = cvt8(w_f + o * 64 + ks * 32 + lg * 8);
    {
        bf16x8 ab2 = {0, 0, 0, 0, 0, 0, 0, 0};
        if (lg == 0) ab2[0] = f2bf(b_f[o]);
        afw[2] = ab2;
    }
    bf16x8 ones = {0, 0, 0, 0, 0, 0, 0, 0};
    if (lr == 0) {
#pragma unroll
        for (int d = 0; d < 8; ++d) ones[d] = (short)0x3F80;
    }

    // ---- pair-prefetch registers (live within one loop body only)
    bf16x8 sA, sB;
    float4 aA0, aA1, aB0, aB1;
    float4 px0, px1, px2, px3;
    float  ab;

    // ---- load + stage pair 4b+0
    {
        const int p = 4 * b, t = p & 63;
        const short* Ab = adjm + ((size_t)p << 12);
        const float* At = Ast  + ((size_t)t << 12);
        const float* Xb = x    + ((size_t)p << 12);
        sA  = *(const bf16x8*)(Ab + row0 * 64 + c8);
        aA0 = *(const float4*)(At + row0 * 64 + c8);
        aA1 = *(const float4*)(At + row0 * 64 + c8 + 4);
        sB  = *(const bf16x8*)(Ab + row1 * 64 + c8);
        aB0 = *(const float4*)(At + row1 * 64 + c8);
        aB1 = *(const float4*)(At + row1 * 64 + c8 + 4);
        px0 = *(const float4*)(Xb + jx * 64 + cx0);
        px1 = *(const float4*)(Xb + jx * 64 + cx0 + 4);
        px2 = *(const float4*)(Xb + jx * 64 + cx0 + 8);
        px3 = *(const float4*)(Xb + jx * 64 + cx0 + 12);
        ab  = alpha * b_rm[t];
    }
    {
        bf16x8 xrA = cvt8f(px0, px1);
        bf16x8 xrB = cvt8f(px2, px3);
        *(bf16x8*)(adjs + row0 * 72 + c8) = fuse8(sA, aA0, aA1, ab);
        *(bf16x8*)(adjs + row1 * 72 + c8) = fuse8(sB, aB0, aB1, ab);
#pragma unroll
        for (int d = 0; d < 8; ++d) {
            xT[(cx0 + d) * 72 + gx0 + jx]     = xrA[d];
            xT[(cx0 + 8 + d) * 72 + gx0 + jx] = xrB[d];
        }
    }
    if (tid < 128) {
        int row = tid >> 1, cz = 80 + (tid & 1) * 8;
        bf16x8 z = {0, 0, 0, 0, 0, 0, 0, 0};
        *(bf16x8*)(P + row * 104 + cz) = z;          // zero once
    }
    __syncthreads();

#pragma unroll
    for (int pp = 0; pp < 4; ++pp) {
        const int pair = 4 * b + pp;

        // ---- hoist current fragments from LDS
        bf16x8 adjA[4][2], bx[2];
#pragma unroll
        for (int mt = 0; mt < 4; ++mt)
#pragma unroll
            for (int ks = 0; ks < 2; ++ks)
                adjA[mt][ks] = *(const bf16x8*)(adjs + (mt * 16 + lr) * 72
                                                + ks * 32 + lg * 8);
#pragma unroll
        for (int ks = 0; ks < 2; ++ks)
            bx[ks] = *(const bf16x8*)(xT + (w * 16 + lr) * 72 + w * 8
                                      + ks * 32 + lg * 8);

        // ---- T14: issue next pair's global loads (in flight during MFMAs)
        if (pp < 3) {
            const int pn = pair + 1, tn = pn & 63;
            const short* Ab = adjm + ((size_t)pn << 12);
            const float* At = Ast  + ((size_t)tn << 12);
            const float* Xb = x    + ((size_t)pn << 12);
            sA  = *(const bf16x8*)(Ab + row0 * 64 + c8);
            aA0 = *(const float4*)(At + row0 * 64 + c8);
            aA1 = *(const float4*)(At + row0 * 64 + c8 + 4);
            sB  = *(const bf16x8*)(Ab + row1 * 64 + c8);
            aB0 = *(const float4*)(At + row1 * 64 + c8);
            aB1 = *(const float4*)(At + row1 * 64 + c8 + 4);
            px0 = *(const float4*)(Xb + jx * 64 + cx0);
            px1 = *(const float4*)(Xb + jx * 64 + cx0 + 4);
            px2 = *(const float4*)(Xb + jx * 64 + cx0 + 8);
            px3 = *(const float4*)(Xb + jx * 64 + cx0 + 12);
            ab  = alpha * b_rm[tn];
        }

        // ---- phase 1: P = adj @ x  (wave w -> c-tile w; wave0 ones-col)
        {
            f32x4 acc[4];
#pragma unroll
            for (int mt = 0; mt < 4; ++mt) acc[mt] = (f32x4){0.f, 0.f, 0.f, 0.f};
#pragma unroll
            for (int ks = 0; ks < 2; ++ks)
#pragma unroll
                for (int mt = 0; mt < 4; ++mt)
                    acc[mt] = MFMA16(adjA[mt][ks], bx[ks], acc[mt]);   // D[i][c]
#pragma unroll
            for (int mt = 0; mt < 4; ++mt)
#pragma unroll
                for (int e = 0; e < 4; ++e)
                    P[(mt * 16 + lg * 4 + e) * 104 + w * 16 + lr] =
                        f2bf(acc[mt][e]);
            if (w == 0) {
                f32x4 accO[4];
#pragma unroll
                for (int mt = 0; mt < 4; ++mt)
                    accO[mt] = (f32x4){0.f, 0.f, 0.f, 0.f};
#pragma unroll
                for (int ks = 0; ks < 2; ++ks)
#pragma unroll
                    for (int mt = 0; mt < 4; ++mt)
                        accO[mt] = MFMA16(adjA[mt][ks], ones, accO[mt]);
#pragma unroll
                for (int mt = 0; mt < 4; ++mt)
#pragma unroll
                    for (int e = 0; e < 4; ++e)
                        P[(mt * 16 + lg * 4 + e) * 104 + 64 + lr] =
                            f2bf(accO[mt][e]);
            }
        }
        __syncthreads();

        // ---- phase 2: out = W_aug @ P  (reads only P + registers)
        {
            float* Ob = out + ((size_t)pair << 12);
#pragma unroll
            for (int nt = 0; nt < 4; ++nt) {
                const int i = nt * 16 + lr;
                bf16x8 bP[3];
#pragma unroll
                for (int ks = 0; ks < 3; ++ks)
                    bP[ks] = *(const bf16x8*)(P + i * 104 + ks * 32 + lg * 8);
                f32x4 acc = (f32x4){0.f, 0.f, 0.f, 0.f};
#pragma unroll
                for (int ks = 0; ks < 3; ++ks)
                    acc = MFMA16(afw[ks], bP[ks], acc);         // D[o][i]
                *(f32x4*)(Ob + i * 64 + w * 16 + lg * 4) = acc;
            }
        }
        // ---- stage next pair (safe: phase2 reads only P)
        if (pp < 3) {
            bf16x8 xrA = cvt8f(px0, px1);
            bf16x8 xrB = cvt8f(px2, px3);
            *(bf16x8*)(adjs + row0 * 72 + c8) = fuse8(sA, aA0, aA1, ab);
            *(bf16x8*)(adjs + row1 * 72 + c8) = fuse8(sB, aB0, aB1, ab);
#pragma unroll
            for (int d = 0; d < 8; ++d) {
                xT[(cx0 + d) * 72 + gx0 + jx]     = xrA[d];
                xT[(cx0 + 8 + d) * 72 + gx0 + jx] = xrB[d];
            }
        }
        __syncthreads();    // P-reads done before next phase1; LDS staged
    }
}

// ---------------------------------------------------------------------------
extern "C" void kernel_launch(void* const* d_in, const int* in_sizes, int n_in,
                              void* d_out, int out_size, void* d_ws, size_t ws_size,
                              hipStream_t stream)
{
    const float* x    = (const float*)d_in[0];
    const float* A    = (const float*)d_in[1];
    const float* w_m1 = (const float*)d_in[2];
    const float* b_m1 = (const float*)d_in[3];
    const float* w_m2 = (const float*)d_in[4];
    const float* b_m2 = (const float*)d_in[5];
    const float* w_rm = (const float*)d_in[6];
    const float* b_rm = (const float*)d_in[7];
    const float* w_f  = (const float*)d_in[8];
    const float* b_f  = (const float*)d_in[9];
    const int*   alpha = (const int*)d_in[10];

    // ws layout: adjm [0,33.5MB), m1T [34,36), m2T [36,38).
    char* ws = (char*)d_ws;
    short* adjm = (short*)(ws);
    float* m1T = (float*)(ws + (size_t)34 * 1024 * 1024);
    float* m2T = (float*)(ws + (size_t)36 * 1024 * 1024);
    float* out = (float*)d_out;

    k0_proj<<<dim3(512), dim3(512), 0, stream>>>(x, w_m1, b_m1, w_m2, b_m2,
                                                 m1T, m2T);
    k1_adj<<<dim3(256), dim3(1024), 0, stream>>>(w_rm, m1T, m2T, alpha, adjm);
    k2_out<<<dim3(1024), dim3(256), 0, stream>>>(adjm, x, A, b_rm, alpha,
                                                 w_f, b_f, out);
}

// Round 23
// 62.364 us; speedup vs baseline: 1.0799x; 1.0799x over previous
//
#include <hip/hip_runtime.h>
#include <hip/hip_bf16.h>

// ---------------------------------------------------------------------------
// DSTDGC R23 = R21 restored (62.6 us best).  R22's LDS-staged k1 output
// regressed +4.7us: k1 is latency-bound, its global stores are fire-and-
// forget, so write amplification was off the critical path; the staging
// added barriers + an LDS round-trip ON the critical path.
// k0_proj: m-projections only, 512 blk x 512 thr.
// k1_adj: block (n, i-chunk of 16), 1024 thr, grid 256; jt-outer transient
//   bfr; staging amortized over 16 i.
// k2_out: T14 depth-4, direct f32 x reads (L3-resident), fused epilogue.
// ---------------------------------------------------------------------------

typedef float  f32x4  __attribute__((ext_vector_type(4)));
typedef short  bf16x8 __attribute__((ext_vector_type(8)));
typedef short  bf16x4 __attribute__((ext_vector_type(4)));

static __device__ __forceinline__ short f2bf(float f) {
    __hip_bfloat16 h = __float2bfloat16(f);     // RNE; compiler packs pairs
    return *reinterpret_cast<short*>(&h);
}

static __device__ __forceinline__ float bf2f(short s) {
    return __uint_as_float(((unsigned)(unsigned short)s) << 16);
}

static __device__ __forceinline__ bf16x8 cvt8f(const float4 a, const float4 b) {
    bf16x8 r;
    r[0] = f2bf(a.x); r[1] = f2bf(a.y); r[2] = f2bf(a.z); r[3] = f2bf(a.w);
    r[4] = f2bf(b.x); r[5] = f2bf(b.y); r[6] = f2bf(b.z); r[7] = f2bf(b.w);
    return r;
}

static __device__ __forceinline__ bf16x8 cvt8(const float* p) {
    return cvt8f(*(const float4*)p, *(const float4*)(p + 4));
}

// tanh(x) = 1 - 2/(exp(2x)+1)
static __device__ __forceinline__ float tanh_fast(float x) {
    float e = __expf(2.0f * x);
    return 1.0f - 2.0f * __builtin_amdgcn_rcpf(e + 1.0f);
}

static __device__ __forceinline__ float dot4(float4 a, float4 b) {
    return a.x * b.x + a.y * b.y + a.z * b.z + a.w * b.w;
}

static __device__ __forceinline__ float alpha_decode(const int* p) {
    int raw = p[0];
    unsigned ur = (unsigned)(raw < 0 ? -raw : raw);
    return (ur < (1u << 23)) ? (float)raw : __int_as_float(raw);
}

static __device__ __forceinline__ bf16x8 fuse8(bf16x8 s, float4 a0, float4 a1,
                                               float ab) {
    bf16x8 r;
    r[0] = f2bf(bf2f(s[0]) + a0.x + ab);
    r[1] = f2bf(bf2f(s[1]) + a0.y + ab);
    r[2] = f2bf(bf2f(s[2]) + a0.z + ab);
    r[3] = f2bf(bf2f(s[3]) + a0.w + ab);
    r[4] = f2bf(bf2f(s[4]) + a1.x + ab);
    r[5] = f2bf(bf2f(s[5]) + a1.y + ab);
    r[6] = f2bf(bf2f(s[6]) + a1.z + ab);
    r[7] = f2bf(bf2f(s[7]) + a1.w + ab);
    return r;
}

#define MFMA16(a, b, c) __builtin_amdgcn_mfma_f32_16x16x32_bf16((a), (b), (c), 0, 0, 0)

// ---------------------------------------------------------------------------
// K0_proj: m-projections only.  Block b = n*8 + vc (v0 = vc*8), 512 thr.
// ---------------------------------------------------------------------------
__global__ __launch_bounds__(512) void k0_proj(
    const float* __restrict__ x,
    const float* __restrict__ w_m1, const float* __restrict__ b_m1,
    const float* __restrict__ w_m2, const float* __restrict__ b_m2,
    float* __restrict__ m1T, float* __restrict__ m2T)
{
    __shared__ float msT[4][8][68];     // [sel][vv][t], stride 68 (f4-aligned)

    const int b   = blockIdx.x;         // n*8 + vc
    const int n   = b >> 3;
    const int v0  = (b & 7) * 8;
    const int tid = threadIdx.x;
    const int tl  = tid >> 6;           // 0..7
    const int vv  = (tid >> 3) & 7;     // 0..7
    const int cg  = tid & 7;            // 0..7
    const int c0  = cg * 8;

    const float4 w10 = *(const float4*)(w_m1 + c0);
    const float4 w11 = *(const float4*)(w_m1 + c0 + 4);
    const float4 w20 = *(const float4*)(w_m1 + 64 + c0);
    const float4 w21 = *(const float4*)(w_m1 + 64 + c0 + 4);
    const float4 w30 = *(const float4*)(w_m2 + c0);
    const float4 w31 = *(const float4*)(w_m2 + c0 + 4);
    const float4 w40 = *(const float4*)(w_m2 + 64 + c0);
    const float4 w41 = *(const float4*)(w_m2 + 64 + c0 + 4);

#pragma unroll 2
    for (int it = 0; it < 8; ++it) {
        const int t = it * 8 + tl;
        const size_t R = ((size_t)(n * 64 + t)) * 64 + (v0 + vv);
        const float* xp = x + (R << 6) + c0;
        const float4 a0 = *(const float4*)xp;
        const float4 a1 = *(const float4*)(xp + 4);

        float s0 = dot4(a0, w10) + dot4(a1, w11);
        float s1 = dot4(a0, w20) + dot4(a1, w21);
        float s2 = dot4(a0, w30) + dot4(a1, w31);
        float s3 = dot4(a0, w40) + dot4(a1, w41);

#pragma unroll
        for (int m = 1; m < 8; m <<= 1) {
            s0 += __shfl_xor(s0, m);
            s1 += __shfl_xor(s1, m);
            s2 += __shfl_xor(s2, m);
            s3 += __shfl_xor(s3, m);
        }
        if (cg < 4) {                   // per-t regions disjoint -> no barrier
            float s = (cg == 0) ? s0 : (cg == 1) ? s1 : (cg == 2) ? s2 : s3;
            msT[cg][vv][t] = s;
        }
    }
    __syncthreads();

    {
        const int m   = tid >> 8;        // 0: m1, 1: m2
        const int rem = tid & 255;
        const int vv2 = rem >> 5;        // 0..7
        const int k0  = (rem & 31) * 4;  // 0..124
        const int r   = k0 >> 6;
        const int sel = m * 2 + r;
        const int t0  = k0 & 63;
        float4 val = *(const float4*)&msT[sel][vv2][t0];
        const float bias = (m == 0) ? b_m1[r] : b_m2[r];
        val.x += bias; val.y += bias; val.z += bias; val.w += bias;
        float* dst = ((m == 0) ? m1T : m2T) + n * 8192 + (v0 + vv2) * 128 + k0;
        *(float4*)dst = val;
    }
}

// ---------------------------------------------------------------------------
// K1: block (n, i-chunk of 16), 1024 thr, grid 256.  R19 body, wave = one i.
// ---------------------------------------------------------------------------
__global__ __launch_bounds__(1024) void k1_adj(
    const float* __restrict__ w_rm,
    const float* __restrict__ m1T,  const float* __restrict__ m2T,
    const int* __restrict__ alpha_p,
    short* __restrict__ adjm)
{
    __shared__ float m2s[64 * 132];     // [j][k] f32 stride 132     (33.8 KB)
    __shared__ short wrs[64 * 132];     // [t][k] bf16*alpha, s=132  (16.9 KB)

    const int b   = blockIdx.x;         // n*4 + ic
    const int n   = b >> 2;
    const int i0  = (b & 3) * 16;
    const int tid = threadIdx.x;
    const int l = tid & 63, w = tid >> 6;       // w = 0..15
    const int lr = l & 15, lg = l >> 4;
    const int ig = i0 + w;

    const float alpha = alpha_decode(alpha_p);

    // ---- issue m1 row loads FIRST (latency hides under staging)
    float4 m1r[8];
#pragma unroll
    for (int kt = 0; kt < 4; ++kt) {
        const float* p = m1T + n * 8192 + ig * 128 + kt * 32 + lg * 8;
        m1r[kt * 2 + 0] = *(const float4*)p;
        m1r[kt * 2 + 1] = *(const float4*)(p + 4);
    }

    {
        const float4* src = (const float4*)(m2T + n * 8192);
        for (int it = tid; it < 2048; it += 1024) {
            int j = it >> 5, q = it & 31;
            *(float4*)(m2s + j * 132 + q * 4) = src[it];
        }
    }
    {
        const float4* src = (const float4*)w_rm;
        for (int it = tid; it < 2048; it += 1024) {
            int t = it >> 5, q = it & 31;
            float4 v = src[it];
            bf16x4 pv;
            pv[0] = f2bf(alpha * v.x);
            pv[1] = f2bf(alpha * v.y);
            pv[2] = f2bf(alpha * v.z);
            pv[3] = f2bf(alpha * v.w);
            *(bf16x4*)(wrs + t * 132 + q * 4) = pv;
        }
    }
    __syncthreads();

    short* adjb = adjm + ((size_t)n << 18) + (ig << 6);

#pragma unroll 1
    for (int jt = 0; jt < 4; ++jt) {
        const float* m2row = m2s + (jt * 16 + lr) * 132;
        bf16x8 bfr[4];
#pragma unroll
        for (int kt = 0; kt < 4; ++kt) {
            const int k0 = kt * 32 + lg * 8;
            float4 b0 = *(const float4*)(m2row + k0);
            float4 b1 = *(const float4*)(m2row + k0 + 4);
            float4 a0 = m1r[kt * 2], a1 = m1r[kt * 2 + 1];
            bfr[kt][0] = f2bf(tanh_fast(a0.x - b0.x));
            bfr[kt][1] = f2bf(tanh_fast(a0.y - b0.y));
            bfr[kt][2] = f2bf(tanh_fast(a0.z - b0.z));
            bfr[kt][3] = f2bf(tanh_fast(a0.w - b0.w));
            bfr[kt][4] = f2bf(tanh_fast(a1.x - b1.x));
            bfr[kt][5] = f2bf(tanh_fast(a1.y - b1.y));
            bfr[kt][6] = f2bf(tanh_fast(a1.z - b1.z));
            bfr[kt][7] = f2bf(tanh_fast(a1.w - b1.w));
        }

        const int j0 = jt * 16 + lg * 4;
#pragma unroll
        for (int q = 0; q < 4; ++q) {
            const int tq = q * 16 + lr;
            bf16x8 af[4];
#pragma unroll
            for (int kt = 0; kt < 4; ++kt)
                af[kt] = *(const bf16x8*)(wrs + tq * 132 + kt * 32 + lg * 8);
            f32x4 acc = (f32x4){0.f, 0.f, 0.f, 0.f};
#pragma unroll
            for (int kt = 0; kt < 4; ++kt)
                acc = MFMA16(bfr[kt], af[kt], acc);             // D[j][t]
            bf16x4 pv;
            pv[0] = f2bf(acc[0]);
            pv[1] = f2bf(acc[1]);
            pv[2] = f2bf(acc[2]);
            pv[3] = f2bf(acc[3]);
            *(bf16x4*)(adjb + ((size_t)tq << 12) + j0) = pv;    // 8B store
        }
    }
}

// ---------------------------------------------------------------------------
// K2: block = FOUR consecutive (n,t) pairs, 256 thr, grid 1024.  T14 depth-4.
//   x read DIRECTLY as f32 (L3-resident); cvt fused into staging.  (R19)
// ---------------------------------------------------------------------------
__global__ __launch_bounds__(256) void k2_out(
    const short* __restrict__ adjm, const float* __restrict__ x,
    const float* __restrict__ Ast,  const float* __restrict__ b_rm,
    const int* __restrict__ alpha_p,
    const float* __restrict__ w_f,  const float* __restrict__ b_f,
    float* __restrict__ out)
{
    __shared__ short adjs[64 * 72];     // [i][j] ready-adj bf16      (9.2 KB)
    __shared__ short xT[64 * 72 + 32];  // [c][j], off c*72+(c>>4)*8  (9.3 KB)
    __shared__ short P[64 * 104];       // [i][c]                    (13.3 KB)

    const int b   = blockIdx.x;         // pairs 4b .. 4b+3
    const int tid = threadIdx.x;
    const int l = tid & 63, w = tid >> 6;
    const int lr = l & 15, lg = l >> 4;

    const float alpha = alpha_decode(alpha_p);

    const int row0 = tid >> 3;          // 0..31
    const int row1 = row0 + 32;         // 32..63
    const int c8   = (tid & 7) * 8;
    const int jx   = tid >> 2;
    const int cx0  = (tid & 3) * 16;
    const int gx0  = (cx0 >> 4) * 8;

    // ---- w_f / b_f / ones fragments: shared across all 4 pairs
    const int o = w * 16 + lr;
    bf16x8 afw[3];
#pragma unroll
    for (int ks = 0; ks < 2; ++ks)
        afw[ks] = cvt8(w_f + o * 64 + ks * 32 + lg * 8);
    {
        bf16x8 ab2 = {0, 0, 0, 0, 0, 0, 0, 0};
        if (lg == 0) ab2[0] = f2bf(b_f[o]);
        afw[2] = ab2;
    }
    bf16x8 ones = {0, 0, 0, 0, 0, 0, 0, 0};
    if (lr == 0) {
#pragma unroll
        for (int d = 0; d < 8; ++d) ones[d] = (short)0x3F80;
    }

    // ---- pair-prefetch registers (live within one loop body only)
    bf16x8 sA, sB;
    float4 aA0, aA1, aB0, aB1;
    float4 px0, px1, px2, px3;
    float  ab;

    // ---- load + stage pair 4b+0
    {
        const int p = 4 * b, t = p & 63;
        const short* Ab = adjm + ((size_t)p << 12);
        const float* At = Ast  + ((size_t)t << 12);
        const float* Xb = x    + ((size_t)p << 12);
        sA  = *(const bf16x8*)(Ab + row0 * 64 + c8);
        aA0 = *(const float4*)(At + row0 * 64 + c8);
        aA1 = *(const float4*)(At + row0 * 64 + c8 + 4);
        sB  = *(const bf16x8*)(Ab + row1 * 64 + c8);
        aB0 = *(const float4*)(At + row1 * 64 + c8);
        aB1 = *(const float4*)(At + row1 * 64 + c8 + 4);
        px0 = *(const float4*)(Xb + jx * 64 + cx0);
        px1 = *(const float4*)(Xb + jx * 64 + cx0 + 4);
        px2 = *(const float4*)(Xb + jx * 64 + cx0 + 8);
        px3 = *(const float4*)(Xb + jx * 64 + cx0 + 12);
        ab  = alpha * b_rm[t];
    }
    {
        bf16x8 xrA = cvt8f(px0, px1);
        bf16x8 xrB = cvt8f(px2, px3);
        *(bf16x8*)(adjs + row0 * 72 + c8) = fuse8(sA, aA0, aA1, ab);
        *(bf16x8*)(adjs + row1 * 72 + c8) = fuse8(sB, aB0, aB1, ab);
#pragma unroll
        for (int d = 0; d < 8; ++d) {
            xT[(cx0 + d) * 72 + gx0 + jx]     = xrA[d];
            xT[(cx0 + 8 + d) * 72 + gx0 + jx] = xrB[d];
        }
    }
    if (tid < 128) {
        int row = tid >> 1, cz = 80 + (tid & 1) * 8;
        bf16x8 z = {0, 0, 0, 0, 0, 0, 0, 0};
        *(bf16x8*)(P + row * 104 + cz) = z;          // zero once
    }
    __syncthreads();

#pragma unroll
    for (int pp = 0; pp < 4; ++pp) {
        const int pair = 4 * b + pp;

        // ---- hoist current fragments from LDS
        bf16x8 adjA[4][2], bx[2];
#pragma unroll
        for (int mt = 0; mt < 4; ++mt)
#pragma unroll
            for (int ks = 0; ks < 2; ++ks)
                adjA[mt][ks] = *(const bf16x8*)(adjs + (mt * 16 + lr) * 72
                                                + ks * 32 + lg * 8);
#pragma unroll
        for (int ks = 0; ks < 2; ++ks)
            bx[ks] = *(const bf16x8*)(xT + (w * 16 + lr) * 72 + w * 8
                                      + ks * 32 + lg * 8);

        // ---- T14: issue next pair's global loads (in flight during MFMAs)
        if (pp < 3) {
            const int pn = pair + 1, tn = pn & 63;
            const short* Ab = adjm + ((size_t)pn << 12);
            const float* At = Ast  + ((size_t)tn << 12);
            const float* Xb = x    + ((size_t)pn << 12);
            sA  = *(const bf16x8*)(Ab + row0 * 64 + c8);
            aA0 = *(const float4*)(At + row0 * 64 + c8);
            aA1 = *(const float4*)(At + row0 * 64 + c8 + 4);
            sB  = *(const bf16x8*)(Ab + row1 * 64 + c8);
            aB0 = *(const float4*)(At + row1 * 64 + c8);
            aB1 = *(const float4*)(At + row1 * 64 + c8 + 4);
            px0 = *(const float4*)(Xb + jx * 64 + cx0);
            px1 = *(const float4*)(Xb + jx * 64 + cx0 + 4);
            px2 = *(const float4*)(Xb + jx * 64 + cx0 + 8);
            px3 = *(const float4*)(Xb + jx * 64 + cx0 + 12);
            ab  = alpha * b_rm[tn];
        }

        // ---- phase 1: P = adj @ x  (wave w -> c-tile w; wave0 ones-col)
        {
            f32x4 acc[4];
#pragma unroll
            for (int mt = 0; mt < 4; ++mt) acc[mt] = (f32x4){0.f, 0.f, 0.f, 0.f};
#pragma unroll
            for (int ks = 0; ks < 2; ++ks)
#pragma unroll
                for (int mt = 0; mt < 4; ++mt)
                    acc[mt] = MFMA16(adjA[mt][ks], bx[ks], acc[mt]);   // D[i][c]
#pragma unroll
            for (int mt = 0; mt < 4; ++mt)
#pragma unroll
                for (int e = 0; e < 4; ++e)
                    P[(mt * 16 + lg * 4 + e) * 104 + w * 16 + lr] =
                        f2bf(acc[mt][e]);
            if (w == 0) {
                f32x4 accO[4];
#pragma unroll
                for (int mt = 0; mt < 4; ++mt)
                    accO[mt] = (f32x4){0.f, 0.f, 0.f, 0.f};
#pragma unroll
                for (int ks = 0; ks < 2; ++ks)
#pragma unroll
                    for (int mt = 0; mt < 4; ++mt)
                        accO[mt] = MFMA16(adjA[mt][ks], ones, accO[mt]);
#pragma unroll
                for (int mt = 0; mt < 4; ++mt)
#pragma unroll
                    for (int e = 0; e < 4; ++e)
                        P[(mt * 16 + lg * 4 + e) * 104 + 64 + lr] =
                            f2bf(accO[mt][e]);
            }
        }
        __syncthreads();

        // ---- phase 2: out = W_aug @ P  (reads only P + registers)
        {
            float* Ob = out + ((size_t)pair << 12);
#pragma unroll
            for (int nt = 0; nt < 4; ++nt) {
                const int i = nt * 16 + lr;
                bf16x8 bP[3];
#pragma unroll
                for (int ks = 0; ks < 3; ++ks)
                    bP[ks] = *(const bf16x8*)(P + i * 104 + ks * 32 + lg * 8);
                f32x4 acc = (f32x4){0.f, 0.f, 0.f, 0.f};
#pragma unroll
                for (int ks = 0; ks < 3; ++ks)
                    acc = MFMA16(afw[ks], bP[ks], acc);         // D[o][i]
                *(f32x4*)(Ob + i * 64 + w * 16 + lg * 4) = acc;
            }
        }
        // ---- stage next pair (safe: phase2 reads only P)
        if (pp < 3) {
            bf16x8 xrA = cvt8f(px0, px1);
            bf16x8 xrB = cvt8f(px2, px3);
            *(bf16x8*)(adjs + row0 * 72 + c8) = fuse8(sA, aA0, aA1, ab);
            *(bf16x8*)(adjs + row1 * 72 + c8) = fuse8(sB, aB0, aB1, ab);
#pragma unroll
            for (int d = 0; d < 8; ++d) {
                xT[(cx0 + d) * 72 + gx0 + jx]     = xrA[d];
                xT[(cx0 + 8 + d) * 72 + gx0 + jx] = xrB[d];
            }
        }
        __syncthreads();    // P-reads done before next phase1; LDS staged
    }
}

// ---------------------------------------------------------------------------
extern "C" void kernel_launch(void* const* d_in, const int* in_sizes, int n_in,
                              void* d_out, int out_size, void* d_ws, size_t ws_size,
                              hipStream_t stream)
{
    const float* x    = (const float*)d_in[0];
    const float* A    = (const float*)d_in[1];
    const float* w_m1 = (const float*)d_in[2];
    const float* b_m1 = (const float*)d_in[3];
    const float* w_m2 = (const float*)d_in[4];
    const float* b_m2 = (const float*)d_in[5];
    const float* w_rm = (const float*)d_in[6];
    const float* b_rm = (const float*)d_in[7];
    const float* w_f  = (const float*)d_in[8];
    const float* b_f  = (const float*)d_in[9];
    const int*   alpha = (const int*)d_in[10];

    // ws layout: adjm [0,33.5MB), m1T [34,36), m2T [36,38).
    char* ws = (char*)d_ws;
    short* adjm = (short*)(ws);
    float* m1T = (float*)(ws + (size_t)34 * 1024 * 1024);
    float* m2T = (float*)(ws + (size_t)36 * 1024 * 1024);
    float* out = (float*)d_out;

    k0_proj<<<dim3(512), dim3(512), 0, stream>>>(x, w_m1, b_m1, w_m2, b_m2,
                                                 m1T, m2T);
    k1_adj<<<dim3(256), dim3(1024), 0, stream>>>(w_rm, m1T, m2T, alpha, adjm);
    k2_out<<<dim3(1024), dim3(256), 0, stream>>>(adjm, x, A, b_rm, alpha,
                                                 w_f, b_f, out);
}